// Round 5
// baseline (287.453 us; speedup 1.0000x reference)
//
#include <hip/hip_runtime.h>
#include <math.h>

// Sparsemax, streaming structure:
//   scan (read-only, running max, no row storage) -> rowmax reduce ->
//   exact candidate re-read by the ~6 threads whose private max > rowmax-1
//   (256B each, L2-hot) -> zero-write burst (independent of tau) ->
//   barrier -> single-wave Newton on the tiny LDS candidate set ->
//   scatter of the <=K nonzeros.
// Low VGPR (no row in registers) => 256-thread blocks, 8 resident rows/CU:
// each row's compute bubbles hide under 7 neighbors' streaming, and the
// tau-dependent write is ~24B instead of 128KB.
// Fallback (K > CAP, adversarial only): block-wide Newton re-reading X.

constexpr int D       = 32000;
constexpr int NV4     = D / 4;          // 8000 float4 per row
constexpr int THREADS = 256;
constexpr int NWAVES  = THREADS / 64;   // 4 waves
constexpr int VPT     = 32;             // 256*32 = 8192 float4 slots >= 8000
constexpr int CAP     = 1024;           // candidate capacity (8KB LDS)

__global__ __launch_bounds__(THREADS, 8)   // 8 waves/SIMD -> 8 blocks/CU
void sparsemax_stream(const float* __restrict__ X, float* __restrict__ Y) {
    const int row  = blockIdx.x;
    const int tid  = threadIdx.x;
    const int wid  = tid >> 6;
    const int lane = tid & 63;

    const float4* xr = reinterpret_cast<const float4*>(X + (size_t)row * D);
    float4*       yr = reinterpret_cast<float4*>(Y + (size_t)row * D);

    __shared__ float sa[NWAVES];
    __shared__ float sb[NWAVES];
    __shared__ float cval[CAP];
    __shared__ int   cidx[CAP];
    __shared__ int   cnt;

    if (tid == 0) cnt = 0;

    // ---- scan: read-only stream, per-component running max ----
    float mx = -INFINITY, my = -INFINITY, mz = -INFINITY, mw = -INFINITY;
    #pragma unroll
    for (int j = 0; j < VPT; ++j) {
        const int idx = tid + j * THREADS;
        if (idx < NV4) {
            const float4 v = xr[idx];
            mx = fmaxf(mx, v.x);
            my = fmaxf(my, v.y);
            mz = fmaxf(mz, v.z);
            mw = fmaxf(mw, v.w);
        }
    }
    const float m_t = fmaxf(fmaxf(mx, my), fmaxf(mz, mw));

    // ---- block max ----
    float m = m_t;
    #pragma unroll
    for (int off = 32; off >= 1; off >>= 1)
        m = fmaxf(m, __shfl_xor(m, off, 64));
    if (lane == 0) sa[wid] = m;
    __syncthreads();                      // also orders cnt=0 vs atomics below
    float rowmax = sa[0];
    #pragma unroll
    for (int w = 1; w < NWAVES; ++w) rowmax = fmaxf(rowmax, sa[w]);
    const float thresh = rowmax - 1.0f;

    // ---- exact candidate collection: only threads that can hold one re-read ----
    if (m_t > thresh) {                   // ~6 threads per row
        #pragma unroll 4
        for (int j = 0; j < VPT; ++j) {
            const int idx = tid + j * THREADS;
            if (idx < NV4) {
                const float4 v = xr[idx]; // L2-hot (just streamed)
                const int base = idx * 4;
                if (v.x > thresh) { int i = atomicAdd(&cnt, 1); if (i < CAP) { cval[i] = v.x; cidx[i] = base + 0; } }
                if (v.y > thresh) { int i = atomicAdd(&cnt, 1); if (i < CAP) { cval[i] = v.y; cidx[i] = base + 1; } }
                if (v.z > thresh) { int i = atomicAdd(&cnt, 1); if (i < CAP) { cval[i] = v.z; cidx[i] = base + 2; } }
                if (v.w > thresh) { int i = atomicAdd(&cnt, 1); if (i < CAP) { cval[i] = v.w; cidx[i] = base + 3; } }
            }
        }
    }

    // ---- zero-write burst: independent of tau ----
    const float4 zero4 = make_float4(0.0f, 0.0f, 0.0f, 0.0f);
    #pragma unroll
    for (int j = 0; j < VPT; ++j) {
        const int idx = tid + j * THREADS;
        if (idx < NV4) yr[idx] = zero4;
    }

    __syncthreads();                      // drains zero stores; candidates visible
    const int K = cnt;

    if (K <= CAP) {
        // ---- single-wave Newton + scatter of the <=K nonzeros ----
        if (wid == 0) {
            float t = thresh;
            for (int it = 0; it < 60; ++it) {
                float s = 0.0f, c = 0.0f;
                for (int i = lane; i < K; i += 64) {
                    const float v = cval[i] - t;
                    if (v > 0.0f) { s += v; c += 1.0f; }
                }
                #pragma unroll
                for (int off = 32; off >= 1; off >>= 1) {
                    s += __shfl_xor(s, off, 64);
                    c += __shfl_xor(c, off, 64);
                }
                const float f = s - 1.0f;
                if (f <= 1e-6f) break;
                const float nt = t + f / c;   // c >= 1 (rowmax is always active)
                if (nt == t) break;
                t = nt;
            }
            float s = 0.0f;
            for (int i = lane; i < K; i += 64) s += fmaxf(cval[i] - t, 0.0f);
            #pragma unroll
            for (int off = 32; off >= 1; off >>= 1) s += __shfl_xor(s, off, 64);
            const float inv = 1.0f / s;
            float* yrow = Y + (size_t)row * D;
            for (int i = lane; i < K; i += 64)
                yrow[cidx[i]] = fmaxf(cval[i] - t, 0.0f) * inv;
        }
        // other waves: done (zeros already written above)
    } else {
        // ---- fallback (adversarial inputs only): block Newton re-reading X ----
        float tau = thresh;
        for (int it = 0; it < 60; ++it) {
            float s = 0.0f, c = 0.0f;
            for (int j = 0; j < VPT; ++j) {
                const int idx = tid + j * THREADS;
                if (idx < NV4) {
                    const float4 v = xr[idx];
                    float d;
                    d = v.x - tau; if (d > 0.0f) { s += d; c += 1.0f; }
                    d = v.y - tau; if (d > 0.0f) { s += d; c += 1.0f; }
                    d = v.z - tau; if (d > 0.0f) { s += d; c += 1.0f; }
                    d = v.w - tau; if (d > 0.0f) { s += d; c += 1.0f; }
                }
            }
            #pragma unroll
            for (int off = 32; off >= 1; off >>= 1) {
                s += __shfl_xor(s, off, 64);
                c += __shfl_xor(c, off, 64);
            }
            __syncthreads();
            if (lane == 0) { sa[wid] = s; sb[wid] = c; }
            __syncthreads();
            float S = 0.0f, C = 0.0f;
            #pragma unroll
            for (int w = 0; w < NWAVES; ++w) { S += sa[w]; C += sb[w]; }
            const float f = S - 1.0f;
            if (f <= 1e-6f) break;
            const float nt = tau + f / C;
            if (nt == tau) break;
            tau = nt;
        }
        // final sum + write
        float s = 0.0f;
        for (int j = 0; j < VPT; ++j) {
            const int idx = tid + j * THREADS;
            if (idx < NV4) {
                const float4 v = xr[idx];
                s += fmaxf(v.x - tau, 0.0f);
                s += fmaxf(v.y - tau, 0.0f);
                s += fmaxf(v.z - tau, 0.0f);
                s += fmaxf(v.w - tau, 0.0f);
            }
        }
        #pragma unroll
        for (int off = 32; off >= 1; off >>= 1) s += __shfl_xor(s, off, 64);
        __syncthreads();
        if (lane == 0) sa[wid] = s;
        __syncthreads();
        float S = 0.0f;
        #pragma unroll
        for (int w = 0; w < NWAVES; ++w) S += sa[w];
        const float inv = 1.0f / S;
        for (int j = 0; j < VPT; ++j) {
            const int idx = tid + j * THREADS;
            if (idx < NV4) {
                const float4 v = xr[idx];
                float4 o;
                o.x = fmaxf(v.x - tau, 0.0f) * inv;
                o.y = fmaxf(v.y - tau, 0.0f) * inv;
                o.z = fmaxf(v.z - tau, 0.0f) * inv;
                o.w = fmaxf(v.w - tau, 0.0f) * inv;
                yr[idx] = o;
            }
        }
    }
}

extern "C" void kernel_launch(void* const* d_in, const int* in_sizes, int n_in,
                              void* d_out, int out_size, void* d_ws, size_t ws_size,
                              hipStream_t stream) {
    const float* X = (const float*)d_in[0];
    float*       Y = (float*)d_out;
    const int rows = in_sizes[0] / D;
    sparsemax_stream<<<rows, THREADS, 0, stream>>>(X, Y);
}

// Round 6
// 239.700 us; speedup vs baseline: 1.1992x; 1.1992x over previous
//
#include <hip/hip_runtime.h>
#include <math.h>

// Sparsemax as two sequential PURE-direction HBM streams:
//   Kernel A: custom grid-stride zero-fill of d_out (write-only, ~6.9 TB/s;
//             the runtime's fillBufferAligned ran at 1.65 TB/s in R3 -- too
//             small a grid -- so we roll our own).
//   Kernel B: read-only R2 structure: row -> registers, rowmax, candidate set
//             {x > rowmax-1} (tau only increases from tau0 = rowmax-1, so all
//             final nonzeros are candidates), single-wave Newton on the tiny
//             LDS set, scatter-write of the <=K nonzeros (~24 B/row).
// Mixed-direction streaming caps at the copy rate (6.29 TB/s); sequential
// pure streams each run at their own higher ceiling.
// Fallback (K > CAP, adversarial only): block-wide Newton + full row write.

constexpr int D       = 32000;
constexpr int NV4     = D / 4;          // 8000 float4 per row
constexpr int THREADS = 1024;
constexpr int NWAVES  = THREADS / 64;   // 16 waves
constexpr int VPT     = 8;              // float4 per thread: 8*1024 = 8192 >= 8000
constexpr int CAP     = 2048;           // candidate capacity

__global__ __launch_bounds__(256)
void zero_fill(float4* __restrict__ Y, int n4) {
    const float4 z = make_float4(0.0f, 0.0f, 0.0f, 0.0f);
    int i = blockIdx.x * 256 + threadIdx.x;
    const int stride = gridDim.x * 256;
    for (; i < n4; i += stride) Y[i] = z;
}

__global__ __launch_bounds__(THREADS)
void sparsemax_tau_scatter(const float* __restrict__ X, float* __restrict__ Y) {
    const int row  = blockIdx.x;
    const int tid  = threadIdx.x;
    const int wid  = tid >> 6;
    const int lane = tid & 63;

    const float4* xr = reinterpret_cast<const float4*>(X + (size_t)row * D);

    __shared__ float sa[NWAVES];
    __shared__ float cval[CAP];
    __shared__ int   cidx[CAP];
    __shared__ int   cnt;

    if (tid == 0) cnt = 0;

    // ---- load the whole row into registers (coalesced, 16B/lane) ----
    float4 r[VPT];
    #pragma unroll
    for (int j = 0; j < VPT; ++j) {
        const int idx = tid + j * THREADS;
        if (idx < NV4) {
            r[j] = xr[idx];
        } else {
            r[j] = make_float4(-INFINITY, -INFINITY, -INFINITY, -INFINITY);
        }
    }

    // ---- row max ----
    float m = -INFINITY;
    #pragma unroll
    for (int j = 0; j < VPT; ++j)
        m = fmaxf(m, fmaxf(fmaxf(r[j].x, r[j].y), fmaxf(r[j].z, r[j].w)));
    #pragma unroll
    for (int off = 32; off >= 1; off >>= 1)
        m = fmaxf(m, __shfl_xor(m, off, 64));
    if (lane == 0) sa[wid] = m;
    __syncthreads();                       // also orders cnt=0 vs atomics below
    float rowmax = sa[0];
    #pragma unroll
    for (int w = 1; w < NWAVES; ++w) rowmax = fmaxf(rowmax, sa[w]);

    // ---- collect candidates (value, index) with x > rowmax - 1 ----
    const float thresh = rowmax - 1.0f;
    #pragma unroll
    for (int j = 0; j < VPT; ++j) {
        const int base = (tid + j * THREADS) * 4;
        float v;
        v = r[j].x; if (v > thresh) { int i = atomicAdd(&cnt, 1); if (i < CAP) { cval[i] = v; cidx[i] = base + 0; } }
        v = r[j].y; if (v > thresh) { int i = atomicAdd(&cnt, 1); if (i < CAP) { cval[i] = v; cidx[i] = base + 1; } }
        v = r[j].z; if (v > thresh) { int i = atomicAdd(&cnt, 1); if (i < CAP) { cval[i] = v; cidx[i] = base + 2; } }
        v = r[j].w; if (v > thresh) { int i = atomicAdd(&cnt, 1); if (i < CAP) { cval[i] = v; cidx[i] = base + 3; } }
    }
    __syncthreads();
    const int K = cnt;

    if (K <= CAP) {
        // ---- single-wave Newton + scatter of the <=K nonzeros ----
        if (wid == 0) {
            float t = thresh;
            for (int it = 0; it < 60; ++it) {
                float s = 0.0f, c = 0.0f;
                for (int i = lane; i < K; i += 64) {
                    const float v = cval[i] - t;
                    if (v > 0.0f) { s += v; c += 1.0f; }
                }
                #pragma unroll
                for (int off = 32; off >= 1; off >>= 1) {
                    s += __shfl_xor(s, off, 64);
                    c += __shfl_xor(c, off, 64);
                }
                const float f = s - 1.0f;
                if (f <= 1e-6f) break;
                const float nt = t + f / c;   // c >= 1 (rowmax is always active)
                if (nt == t) break;
                t = nt;
            }
            float s = 0.0f;
            for (int i = lane; i < K; i += 64) s += fmaxf(cval[i] - t, 0.0f);
            #pragma unroll
            for (int off = 32; off >= 1; off >>= 1) s += __shfl_xor(s, off, 64);
            const float inv = 1.0f / s;
            float* yrow = Y + (size_t)row * D;
            for (int i = lane; i < K; i += 64)
                yrow[cidx[i]] = fmaxf(cval[i] - t, 0.0f) * inv;
        }
        // other waves: done (zeros already written by kernel A)
    } else {
        // ---- fallback: block-wide Newton over registers + full row write ----
        __shared__ float fa[NWAVES], fb[NWAVES];
        float tau = thresh;
        for (int it = 0; it < 60; ++it) {
            float s = 0.0f, c = 0.0f;
            #pragma unroll
            for (int j = 0; j < VPT; ++j) {
                float v;
                v = r[j].x - tau; if (v > 0.0f) { s += v; c += 1.0f; }
                v = r[j].y - tau; if (v > 0.0f) { s += v; c += 1.0f; }
                v = r[j].z - tau; if (v > 0.0f) { s += v; c += 1.0f; }
                v = r[j].w - tau; if (v > 0.0f) { s += v; c += 1.0f; }
            }
            #pragma unroll
            for (int off = 32; off >= 1; off >>= 1) {
                s += __shfl_xor(s, off, 64);
                c += __shfl_xor(c, off, 64);
            }
            __syncthreads();
            if (lane == 0) { fa[wid] = s; fb[wid] = c; }
            __syncthreads();
            float S = 0.0f, C = 0.0f;
            #pragma unroll
            for (int w = 0; w < NWAVES; ++w) { S += fa[w]; C += fb[w]; }
            const float f = S - 1.0f;
            if (f <= 1e-6f) break;
            const float nt = tau + f / C;
            if (nt == tau) break;
            tau = nt;
        }
        float s = 0.0f;
        #pragma unroll
        for (int j = 0; j < VPT; ++j) {
            s += fmaxf(r[j].x - tau, 0.0f);
            s += fmaxf(r[j].y - tau, 0.0f);
            s += fmaxf(r[j].z - tau, 0.0f);
            s += fmaxf(r[j].w - tau, 0.0f);
        }
        #pragma unroll
        for (int off = 32; off >= 1; off >>= 1) s += __shfl_xor(s, off, 64);
        __syncthreads();
        if (lane == 0) fa[wid] = s;
        __syncthreads();
        float S = 0.0f;
        #pragma unroll
        for (int w = 0; w < NWAVES; ++w) S += fa[w];
        const float inv = 1.0f / S;

        float4* yr = reinterpret_cast<float4*>(Y + (size_t)row * D);
        #pragma unroll
        for (int j = 0; j < VPT; ++j) {
            const int idx = tid + j * THREADS;
            if (idx < NV4) {
                float4 o;
                o.x = fmaxf(r[j].x - tau, 0.0f) * inv;
                o.y = fmaxf(r[j].y - tau, 0.0f) * inv;
                o.z = fmaxf(r[j].z - tau, 0.0f) * inv;
                o.w = fmaxf(r[j].w - tau, 0.0f) * inv;
                yr[idx] = o;
            }
        }
    }
}

extern "C" void kernel_launch(void* const* d_in, const int* in_sizes, int n_in,
                              void* d_out, int out_size, void* d_ws, size_t ws_size,
                              hipStream_t stream) {
    const float* X = (const float*)d_in[0];
    float*       Y = (float*)d_out;
    const int rows = in_sizes[0] / D;
    const int n4   = out_size / 4;
    zero_fill<<<2048, 256, 0, stream>>>(reinterpret_cast<float4*>(Y), n4);
    sparsemax_tau_scatter<<<rows, THREADS, 0, stream>>>(X, Y);
}

// Round 7
// 208.339 us; speedup vs baseline: 1.3797x; 1.1505x over previous
//
#include <hip/hip_runtime.h>
#include <math.h>

// Sparsemax, fused single-kernel (R2 structure) with the zero-write decoupled
// from Newton:
//   load row -> registers; rowmax reduce; then EVERY thread immediately
//   zero-writes vectors with max comp <= rowmax-1 (99.9% of the row; depends
//   only on rowmax) and defers candidate-containing float4s to LDS.
//   Wave 0 then runs Newton on the tiny deferred set and scatter-writes only
//   those vectors (never zero-written -> no ordering hazard).
// This removes Newton from the critical path of the 512 MB write burst while
// keeping phase-separated read/write bursts (R4 showed interleaving loses;
// R3/R6 showed separate write passes lose).
// Fallback (deferred > CAPV, adversarial only): block-wide Newton over
// registers + full row overwrite (same-thread stores to same addr are ordered).

constexpr int D       = 32000;
constexpr int NV4     = D / 4;          // 8000 float4 per row
constexpr int THREADS = 1024;
constexpr int NWAVES  = THREADS / 64;   // 16 waves
constexpr int VPT     = 8;              // float4 per thread: 8*1024 = 8192 >= 8000
constexpr int CAPV    = 512;            // deferred-vector capacity (10 KB LDS)

__global__ __launch_bounds__(THREADS)
void sparsemax_fused2(const float* __restrict__ X, float* __restrict__ Y) {
    const int row  = blockIdx.x;
    const int tid  = threadIdx.x;
    const int wid  = tid >> 6;
    const int lane = tid & 63;

    const float4* xr = reinterpret_cast<const float4*>(X + (size_t)row * D);
    float4*       yr = reinterpret_cast<float4*>(Y + (size_t)row * D);

    __shared__ float  sa[NWAVES];
    __shared__ float4 dval[CAPV];
    __shared__ int    didx[CAPV];
    __shared__ int    cnt;

    if (tid == 0) cnt = 0;

    // ---- load the whole row into registers (coalesced, 16B/lane) ----
    float4 r[VPT];
    #pragma unroll
    for (int j = 0; j < VPT; ++j) {
        const int idx = tid + j * THREADS;
        if (idx < NV4) {
            r[j] = xr[idx];
        } else {
            r[j] = make_float4(-INFINITY, -INFINITY, -INFINITY, -INFINITY);
        }
    }

    // ---- row max ----
    float m = -INFINITY;
    #pragma unroll
    for (int j = 0; j < VPT; ++j)
        m = fmaxf(m, fmaxf(fmaxf(r[j].x, r[j].y), fmaxf(r[j].z, r[j].w)));
    #pragma unroll
    for (int off = 32; off >= 1; off >>= 1)
        m = fmaxf(m, __shfl_xor(m, off, 64));
    if (lane == 0) sa[wid] = m;
    __syncthreads();                       // also orders cnt=0 vs atomics below
    float rowmax = sa[0];
    #pragma unroll
    for (int w = 1; w < NWAVES; ++w) rowmax = fmaxf(rowmax, sa[w]);
    const float thresh = rowmax - 1.0f;

    // ---- zero-write burst (tau-independent) + defer candidate quads ----
    const float4 zero4 = make_float4(0.0f, 0.0f, 0.0f, 0.0f);
    #pragma unroll
    for (int j = 0; j < VPT; ++j) {
        const int idx = tid + j * THREADS;
        if (idx < NV4) {
            const float4 v = r[j];
            const float vm = fmaxf(fmaxf(v.x, v.y), fmaxf(v.z, v.w));
            if (vm > thresh) {
                int i = atomicAdd(&cnt, 1);
                if (i < CAPV) { dval[i] = v; didx[i] = idx; }
            } else {
                yr[idx] = zero4;
            }
        }
    }
    __syncthreads();                       // LDS candidates visible
    const int K = cnt;                     // deferred quad count (>=1: rowmax quad)

    if (K <= CAPV) {
        // ---- single-wave Newton over deferred quads + scatter ----
        if (wid == 0) {
            float t = thresh;
            for (int it = 0; it < 60; ++it) {
                float s = 0.0f, c = 0.0f;
                for (int i = lane; i < K; i += 64) {
                    const float4 v = dval[i];
                    float d;
                    d = v.x - t; if (d > 0.0f) { s += d; c += 1.0f; }
                    d = v.y - t; if (d > 0.0f) { s += d; c += 1.0f; }
                    d = v.z - t; if (d > 0.0f) { s += d; c += 1.0f; }
                    d = v.w - t; if (d > 0.0f) { s += d; c += 1.0f; }
                }
                #pragma unroll
                for (int off = 32; off >= 1; off >>= 1) {
                    s += __shfl_xor(s, off, 64);
                    c += __shfl_xor(c, off, 64);
                }
                const float f = s - 1.0f;
                if (f <= 1e-6f) break;
                const float nt = t + f / c;   // c >= 1 (rowmax stays active)
                if (nt == t) break;
                t = nt;
            }
            float s = 0.0f;
            for (int i = lane; i < K; i += 64) {
                const float4 v = dval[i];
                s += fmaxf(v.x - t, 0.0f);
                s += fmaxf(v.y - t, 0.0f);
                s += fmaxf(v.z - t, 0.0f);
                s += fmaxf(v.w - t, 0.0f);
            }
            #pragma unroll
            for (int off = 32; off >= 1; off >>= 1) s += __shfl_xor(s, off, 64);
            const float inv = 1.0f / s;
            for (int i = lane; i < K; i += 64) {
                const float4 v = dval[i];
                float4 o;
                o.x = fmaxf(v.x - t, 0.0f) * inv;
                o.y = fmaxf(v.y - t, 0.0f) * inv;
                o.z = fmaxf(v.z - t, 0.0f) * inv;
                o.w = fmaxf(v.w - t, 0.0f) * inv;
                yr[didx[i]] = o;           // only deferred (never zero-written) quads
            }
        }
        // other waves: done (their quads were zero-written above)
    } else {
        // ---- fallback: block-wide Newton over registers + full row write ----
        __shared__ float fa[NWAVES], fb[NWAVES];
        float tau = thresh;
        for (int it = 0; it < 60; ++it) {
            float s = 0.0f, c = 0.0f;
            #pragma unroll
            for (int j = 0; j < VPT; ++j) {
                float v;
                v = r[j].x - tau; if (v > 0.0f) { s += v; c += 1.0f; }
                v = r[j].y - tau; if (v > 0.0f) { s += v; c += 1.0f; }
                v = r[j].z - tau; if (v > 0.0f) { s += v; c += 1.0f; }
                v = r[j].w - tau; if (v > 0.0f) { s += v; c += 1.0f; }
            }
            #pragma unroll
            for (int off = 32; off >= 1; off >>= 1) {
                s += __shfl_xor(s, off, 64);
                c += __shfl_xor(c, off, 64);
            }
            __syncthreads();
            if (lane == 0) { fa[wid] = s; fb[wid] = c; }
            __syncthreads();
            float S = 0.0f, C = 0.0f;
            #pragma unroll
            for (int w = 0; w < NWAVES; ++w) { S += fa[w]; C += fb[w]; }
            const float f = S - 1.0f;
            if (f <= 1e-6f) break;
            const float nt = tau + f / C;
            if (nt == tau) break;
            tau = nt;
        }
        float s = 0.0f;
        #pragma unroll
        for (int j = 0; j < VPT; ++j) {
            s += fmaxf(r[j].x - tau, 0.0f);
            s += fmaxf(r[j].y - tau, 0.0f);
            s += fmaxf(r[j].z - tau, 0.0f);
            s += fmaxf(r[j].w - tau, 0.0f);
        }
        #pragma unroll
        for (int off = 32; off >= 1; off >>= 1) s += __shfl_xor(s, off, 64);
        __syncthreads();
        if (lane == 0) fa[wid] = s;
        __syncthreads();
        float S = 0.0f;
        #pragma unroll
        for (int w = 0; w < NWAVES; ++w) S += fa[w];
        const float inv = 1.0f / S;

        #pragma unroll
        for (int j = 0; j < VPT; ++j) {
            const int idx = tid + j * THREADS;
            if (idx < NV4) {
                float4 o;
                o.x = fmaxf(r[j].x - tau, 0.0f) * inv;
                o.y = fmaxf(r[j].y - tau, 0.0f) * inv;
                o.z = fmaxf(r[j].z - tau, 0.0f) * inv;
                o.w = fmaxf(r[j].w - tau, 0.0f) * inv;
                yr[idx] = o;               // same-thread overwrite is ordered
            }
        }
    }
}

extern "C" void kernel_launch(void* const* d_in, const int* in_sizes, int n_in,
                              void* d_out, int out_size, void* d_ws, size_t ws_size,
                              hipStream_t stream) {
    const float* X = (const float*)d_in[0];
    float*       Y = (float*)d_out;
    const int rows = in_sizes[0] / D;
    sparsemax_fused2<<<rows, THREADS, 0, stream>>>(X, Y);
}

// Round 9
// 196.381 us; speedup vs baseline: 1.4638x; 1.0609x over previous
//
#include <hip/hip_runtime.h>
#include <math.h>

// R2 structure (best measured: 196 us) + NONTEMPORAL loads/stores.
// Both streams are use-once (X read once, Y written once, never re-read), so
// bypassing L1/L2 allocation ('nt' cache modifier) avoids churning 1 GB of
// dead lines through the 4 MiB per-XCD L2s. Only change vs R2.
// NOTE: __builtin_nontemporal_* requires native vector types, not
// HIP_vector_type structs -> use ext_vector_type(4) float.

constexpr int D       = 32000;
constexpr int NV4     = D / 4;          // 8000 float4 per row
constexpr int THREADS = 1024;
constexpr int NWAVES  = THREADS / 64;   // 16 waves
constexpr int VPT     = 8;              // float4 per thread: 8*1024 = 8192 >= 8000
constexpr int CAP     = 2048;           // candidate capacity

typedef float f32x4 __attribute__((ext_vector_type(4)));

__global__ __launch_bounds__(THREADS)
void sparsemax_nt(const float* __restrict__ X, float* __restrict__ Y) {
    const int row  = blockIdx.x;
    const int tid  = threadIdx.x;
    const int wid  = tid >> 6;
    const int lane = tid & 63;

    const f32x4* xr = reinterpret_cast<const f32x4*>(X + (size_t)row * D);
    f32x4*       yr = reinterpret_cast<f32x4*>(Y + (size_t)row * D);

    __shared__ float sa[NWAVES];
    __shared__ float cval[CAP];
    __shared__ int   cidx[CAP];
    __shared__ int   cnt;

    if (tid == 0) cnt = 0;

    // ---- load the whole row into registers (coalesced, 16B/lane, NT) ----
    f32x4 r[VPT];
    #pragma unroll
    for (int j = 0; j < VPT; ++j) {
        const int idx = tid + j * THREADS;
        if (idx < NV4) {
            r[j] = __builtin_nontemporal_load(&xr[idx]);
        } else {
            r[j] = (f32x4){-INFINITY, -INFINITY, -INFINITY, -INFINITY};
        }
    }

    // ---- row max ----
    float m = -INFINITY;
    #pragma unroll
    for (int j = 0; j < VPT; ++j)
        m = fmaxf(m, fmaxf(fmaxf(r[j].x, r[j].y), fmaxf(r[j].z, r[j].w)));
    #pragma unroll
    for (int off = 32; off >= 1; off >>= 1)
        m = fmaxf(m, __shfl_xor(m, off, 64));
    if (lane == 0) sa[wid] = m;
    __syncthreads();                       // also orders cnt=0 vs atomics below
    float rowmax = sa[0];
    #pragma unroll
    for (int w = 1; w < NWAVES; ++w) rowmax = fmaxf(rowmax, sa[w]);

    // ---- collect candidates (value, index) with x > rowmax - 1 ----
    const float thresh = rowmax - 1.0f;
    #pragma unroll
    for (int j = 0; j < VPT; ++j) {
        const int base = (tid + j * THREADS) * 4;
        float v;
        v = r[j].x; if (v > thresh) { int i = atomicAdd(&cnt, 1); if (i < CAP) { cval[i] = v; cidx[i] = base + 0; } }
        v = r[j].y; if (v > thresh) { int i = atomicAdd(&cnt, 1); if (i < CAP) { cval[i] = v; cidx[i] = base + 1; } }
        v = r[j].z; if (v > thresh) { int i = atomicAdd(&cnt, 1); if (i < CAP) { cval[i] = v; cidx[i] = base + 2; } }
        v = r[j].w; if (v > thresh) { int i = atomicAdd(&cnt, 1); if (i < CAP) { cval[i] = v; cidx[i] = base + 3; } }
    }
    __syncthreads();
    const int K = cnt;

    float tau, inv;
    if (K <= CAP) {
        // ---- single-wave Newton over the candidate set ----
        __shared__ float s_tau, s_inv;
        if (wid == 0) {
            float t = thresh;
            for (int it = 0; it < 60; ++it) {
                float s = 0.0f, c = 0.0f;
                for (int i = lane; i < K; i += 64) {
                    const float v = cval[i] - t;
                    if (v > 0.0f) { s += v; c += 1.0f; }
                }
                #pragma unroll
                for (int off = 32; off >= 1; off >>= 1) {
                    s += __shfl_xor(s, off, 64);
                    c += __shfl_xor(c, off, 64);
                }
                const float f = s - 1.0f;
                if (f <= 1e-6f) break;
                const float nt = t + f / c;   // c >= 1 (rowmax is always active)
                if (nt == t) break;
                t = nt;
            }
            float s = 0.0f;
            for (int i = lane; i < K; i += 64) s += fmaxf(cval[i] - t, 0.0f);
            #pragma unroll
            for (int off = 32; off >= 1; off >>= 1) s += __shfl_xor(s, off, 64);
            if (lane == 0) { s_tau = t; s_inv = 1.0f / s; }
        }
        __syncthreads();
        tau = s_tau;
        inv = s_inv;
    } else {
        // ---- fallback: block-wide Newton over full register data ----
        __shared__ float fa[NWAVES], fb[NWAVES];
        tau = thresh;
        for (int it = 0; it < 60; ++it) {
            float s = 0.0f, c = 0.0f;
            #pragma unroll
            for (int j = 0; j < VPT; ++j) {
                float v;
                v = r[j].x - tau; if (v > 0.0f) { s += v; c += 1.0f; }
                v = r[j].y - tau; if (v > 0.0f) { s += v; c += 1.0f; }
                v = r[j].z - tau; if (v > 0.0f) { s += v; c += 1.0f; }
                v = r[j].w - tau; if (v > 0.0f) { s += v; c += 1.0f; }
            }
            #pragma unroll
            for (int off = 32; off >= 1; off >>= 1) {
                s += __shfl_xor(s, off, 64);
                c += __shfl_xor(c, off, 64);
            }
            __syncthreads();
            if (lane == 0) { fa[wid] = s; fb[wid] = c; }
            __syncthreads();
            float S = 0.0f, C = 0.0f;
            #pragma unroll
            for (int w = 0; w < NWAVES; ++w) { S += fa[w]; C += fb[w]; }
            const float f = S - 1.0f;
            if (f <= 1e-6f) break;
            const float nt = tau + f / C;
            if (nt == tau) break;
            tau = nt;
        }
        float s = 0.0f;
        #pragma unroll
        for (int j = 0; j < VPT; ++j) {
            s += fmaxf(r[j].x - tau, 0.0f);
            s += fmaxf(r[j].y - tau, 0.0f);
            s += fmaxf(r[j].z - tau, 0.0f);
            s += fmaxf(r[j].w - tau, 0.0f);
        }
        #pragma unroll
        for (int off = 32; off >= 1; off >>= 1) s += __shfl_xor(s, off, 64);
        __syncthreads();
        if (lane == 0) fa[wid] = s;
        __syncthreads();
        float S = 0.0f;
        #pragma unroll
        for (int w = 0; w < NWAVES; ++w) S += fa[w];
        inv = 1.0f / S;
    }

    // ---- write p = max(x - tau, 0) * inv, coalesced float4 burst (NT) ----
    #pragma unroll
    for (int j = 0; j < VPT; ++j) {
        const int idx = tid + j * THREADS;
        if (idx < NV4) {
            f32x4 o;
            o.x = fmaxf(r[j].x - tau, 0.0f) * inv;
            o.y = fmaxf(r[j].y - tau, 0.0f) * inv;
            o.z = fmaxf(r[j].z - tau, 0.0f) * inv;
            o.w = fmaxf(r[j].w - tau, 0.0f) * inv;
            __builtin_nontemporal_store(o, &yr[idx]);
        }
    }
}

extern "C" void kernel_launch(void* const* d_in, const int* in_sizes, int n_in,
                              void* d_out, int out_size, void* d_ws, size_t ws_size,
                              hipStream_t stream) {
    const float* X = (const float*)d_in[0];
    float*       Y = (float*)d_out;
    const int rows = in_sizes[0] / D;
    sparsemax_nt<<<rows, THREADS, 0, stream>>>(X, Y);
}

// Round 10
// 191.361 us; speedup vs baseline: 1.5021x; 1.0262x over previous
//
#include <hip/hip_runtime.h>
#include <math.h>

// R2/R9 structure with 512-thread blocks (VPT=16) + __launch_bounds__(512,4):
// row stays fully in registers (64 data VGPRs, cap 128 -> no spills), but now
// 2 blocks/CU are resident (16 waves/CU), so one block's load/store bursts
// overlap the other's reduce/Newton bubble. At 1024 threads (~80-100 VGPR)
// only 1 block/CU fit -> strictly serial load->compute->store per CU, ~45 us
// of idle-memory time (196 us vs the 167 us copy-rate floor).
// NT loads/stores kept from R9 (neutral, avoids dead-line L2 churn).

constexpr int D       = 32000;
constexpr int NV4     = D / 4;          // 8000 float4 per row
constexpr int THREADS = 512;
constexpr int NWAVES  = THREADS / 64;   // 8 waves
constexpr int VPT     = 16;             // 512*16 = 8192 float4 slots >= 8000
constexpr int CAP     = 2048;           // candidate capacity

typedef float f32x4 __attribute__((ext_vector_type(4)));

__global__ __launch_bounds__(THREADS, 4)   // 4 waves/SIMD = 2 blocks/CU
void sparsemax_2blk(const float* __restrict__ X, float* __restrict__ Y) {
    const int row  = blockIdx.x;
    const int tid  = threadIdx.x;
    const int wid  = tid >> 6;
    const int lane = tid & 63;

    const f32x4* xr = reinterpret_cast<const f32x4*>(X + (size_t)row * D);
    f32x4*       yr = reinterpret_cast<f32x4*>(Y + (size_t)row * D);

    __shared__ float sa[NWAVES];
    __shared__ float cval[CAP];
    __shared__ int   cidx[CAP];
    __shared__ int   cnt;

    if (tid == 0) cnt = 0;

    // ---- load the whole row into registers (coalesced, 16B/lane, NT) ----
    f32x4 r[VPT];
    #pragma unroll
    for (int j = 0; j < VPT; ++j) {
        const int idx = tid + j * THREADS;
        if (idx < NV4) {
            r[j] = __builtin_nontemporal_load(&xr[idx]);
        } else {
            r[j] = (f32x4){-INFINITY, -INFINITY, -INFINITY, -INFINITY};
        }
    }

    // ---- row max ----
    float m = -INFINITY;
    #pragma unroll
    for (int j = 0; j < VPT; ++j)
        m = fmaxf(m, fmaxf(fmaxf(r[j].x, r[j].y), fmaxf(r[j].z, r[j].w)));
    #pragma unroll
    for (int off = 32; off >= 1; off >>= 1)
        m = fmaxf(m, __shfl_xor(m, off, 64));
    if (lane == 0) sa[wid] = m;
    __syncthreads();                       // also orders cnt=0 vs atomics below
    float rowmax = sa[0];
    #pragma unroll
    for (int w = 1; w < NWAVES; ++w) rowmax = fmaxf(rowmax, sa[w]);

    // ---- collect candidates (value, index) with x > rowmax - 1 ----
    const float thresh = rowmax - 1.0f;
    #pragma unroll
    for (int j = 0; j < VPT; ++j) {
        const int base = (tid + j * THREADS) * 4;
        float v;
        v = r[j].x; if (v > thresh) { int i = atomicAdd(&cnt, 1); if (i < CAP) { cval[i] = v; cidx[i] = base + 0; } }
        v = r[j].y; if (v > thresh) { int i = atomicAdd(&cnt, 1); if (i < CAP) { cval[i] = v; cidx[i] = base + 1; } }
        v = r[j].z; if (v > thresh) { int i = atomicAdd(&cnt, 1); if (i < CAP) { cval[i] = v; cidx[i] = base + 2; } }
        v = r[j].w; if (v > thresh) { int i = atomicAdd(&cnt, 1); if (i < CAP) { cval[i] = v; cidx[i] = base + 3; } }
    }
    __syncthreads();
    const int K = cnt;

    float tau, inv;
    if (K <= CAP) {
        // ---- single-wave Newton over the candidate set ----
        __shared__ float s_tau, s_inv;
        if (wid == 0) {
            float t = thresh;
            for (int it = 0; it < 60; ++it) {
                float s = 0.0f, c = 0.0f;
                for (int i = lane; i < K; i += 64) {
                    const float v = cval[i] - t;
                    if (v > 0.0f) { s += v; c += 1.0f; }
                }
                #pragma unroll
                for (int off = 32; off >= 1; off >>= 1) {
                    s += __shfl_xor(s, off, 64);
                    c += __shfl_xor(c, off, 64);
                }
                const float f = s - 1.0f;
                if (f <= 1e-6f) break;
                const float nt = t + f / c;   // c >= 1 (rowmax is always active)
                if (nt == t) break;
                t = nt;
            }
            float s = 0.0f;
            for (int i = lane; i < K; i += 64) s += fmaxf(cval[i] - t, 0.0f);
            #pragma unroll
            for (int off = 32; off >= 1; off >>= 1) s += __shfl_xor(s, off, 64);
            if (lane == 0) { s_tau = t; s_inv = 1.0f / s; }
        }
        __syncthreads();
        tau = s_tau;
        inv = s_inv;
    } else {
        // ---- fallback: block-wide Newton over full register data ----
        __shared__ float fa[NWAVES], fb[NWAVES];
        tau = thresh;
        for (int it = 0; it < 60; ++it) {
            float s = 0.0f, c = 0.0f;
            #pragma unroll
            for (int j = 0; j < VPT; ++j) {
                float v;
                v = r[j].x - tau; if (v > 0.0f) { s += v; c += 1.0f; }
                v = r[j].y - tau; if (v > 0.0f) { s += v; c += 1.0f; }
                v = r[j].z - tau; if (v > 0.0f) { s += v; c += 1.0f; }
                v = r[j].w - tau; if (v > 0.0f) { s += v; c += 1.0f; }
            }
            #pragma unroll
            for (int off = 32; off >= 1; off >>= 1) {
                s += __shfl_xor(s, off, 64);
                c += __shfl_xor(c, off, 64);
            }
            __syncthreads();
            if (lane == 0) { fa[wid] = s; fb[wid] = c; }
            __syncthreads();
            float S = 0.0f, C = 0.0f;
            #pragma unroll
            for (int w = 0; w < NWAVES; ++w) { S += fa[w]; C += fb[w]; }
            const float f = S - 1.0f;
            if (f <= 1e-6f) break;
            const float nt = tau + f / C;
            if (nt == tau) break;
            tau = nt;
        }
        float s = 0.0f;
        #pragma unroll
        for (int j = 0; j < VPT; ++j) {
            s += fmaxf(r[j].x - tau, 0.0f);
            s += fmaxf(r[j].y - tau, 0.0f);
            s += fmaxf(r[j].z - tau, 0.0f);
            s += fmaxf(r[j].w - tau, 0.0f);
        }
        #pragma unroll
        for (int off = 32; off >= 1; off >>= 1) s += __shfl_xor(s, off, 64);
        __syncthreads();
        if (lane == 0) fa[wid] = s;
        __syncthreads();
        float S = 0.0f;
        #pragma unroll
        for (int w = 0; w < NWAVES; ++w) S += fa[w];
        inv = 1.0f / S;
    }

    // ---- write p = max(x - tau, 0) * inv, coalesced float4 burst (NT) ----
    #pragma unroll
    for (int j = 0; j < VPT; ++j) {
        const int idx = tid + j * THREADS;
        if (idx < NV4) {
            f32x4 o;
            o.x = fmaxf(r[j].x - tau, 0.0f) * inv;
            o.y = fmaxf(r[j].y - tau, 0.0f) * inv;
            o.z = fmaxf(r[j].z - tau, 0.0f) * inv;
            o.w = fmaxf(r[j].w - tau, 0.0f) * inv;
            __builtin_nontemporal_store(o, &yr[idx]);
        }
    }
}

extern "C" void kernel_launch(void* const* d_in, const int* in_sizes, int n_in,
                              void* d_out, int out_size, void* d_ws, size_t ws_size,
                              hipStream_t stream) {
    const float* X = (const float*)d_in[0];
    float*       Y = (float*)d_out;
    const int rows = in_sizes[0] / D;
    sparsemax_2blk<<<rows, THREADS, 0, stream>>>(X, Y);
}